// Round 1
// baseline (17874.310 us; speedup 1.0000x reference)
//
#include <hip/hip_runtime.h>
#include <hip/hip_bf16.h>
#include <math.h>

#define BB   64
#define INP  1024
#define HIDN 2048
#define NPU  256
#define MEMN 4096
#define RR   512
#define DD   512
#define MMU_USED 1537   // 3*D + 1 gate col; remaining 1027 rows of mmu_w are unused by reference

// ---- workspace layout (float units; bf16 block at end) ----
#define OFF_QUERY  ((size_t)0)
#define OFF_WKEY   (OFF_QUERY + (size_t)BB*NPU*DD)
#define OFF_WVAL   (OFF_WKEY  + (size_t)BB*NPU*DD)
#define OFF_RDATA  (OFF_WVAL  + (size_t)BB*NPU*DD)
#define OFF_WGATE  (OFF_RDATA + (size_t)BB*NPU*DD)
#define OFF_WMAX   (OFF_WGATE + (size_t)BB*NPU)
#define OFF_WSUM   (OFF_WMAX  + (size_t)BB*NPU)
#define OFF_GIX    (OFF_WSUM  + (size_t)BB*NPU)
#define OFF_P      (OFF_GIX   + (size_t)BB*1536)
#define OFF_R      (OFF_P     + 1024)
#define OFF_FEND   (OFF_R     + 512)
// swsc (bf16 write scores, B*NPU*MEMN elems) at byte offset OFF_FEND*4

__device__ __forceinline__ float dot4(float4 a, float4 b) {
    return a.x*b.x + a.y*b.y + a.z*b.z + a.w*b.w;
}

// p[i] = sum_h agg_q[h] * proj_w[h,i]
__global__ __launch_bounds__(256) void kP0(const float* __restrict__ proj_w,
                                           const float* __restrict__ agg_q,
                                           float* __restrict__ p) {
    int i = blockIdx.x * 256 + threadIdx.x;      // < 1024
    float acc = 0.f;
    for (int h = 0; h < HIDN; ++h) acc += agg_q[h] * proj_w[(size_t)h * INP + i];
    p[i] = acc;
}

// r[j] = sum_i p[i] * out_w[i,j]
__global__ __launch_bounds__(256) void kP1(const float* __restrict__ out_w,
                                           const float* __restrict__ p,
                                           float* __restrict__ r) {
    int j = blockIdx.x * 256 + threadIdx.x;      // < 512
    float acc = 0.f;
    for (int i = 0; i < INP; ++i) acc += p[i] * out_w[(size_t)i * RR + j];
    r[j] = acc;
}

// pass-through copy hidden_state -> out hidden region (rows >= A keep original)
__global__ __launch_bounds__(256) void kCopyHidden(const float4* __restrict__ src,
                                                   float4* __restrict__ dst) {
    int idx = blockIdx.x * 256 + threadIdx.x;    // grid 2048 -> 524288 threads
#pragma unroll
    for (int j = 0; j < 4; ++j) dst[idx + j * 524288] = src[idx + j * 524288];
}

// gix[b,n] = b_ih[n] + sum_{i<1024} x[b,i]*W_ih[n,i]   (x part of GRU input GEMM, per-b only)
__global__ __launch_bounds__(256) void kGix(const float* __restrict__ x,
                                            const float* __restrict__ w_ih,
                                            const float* __restrict__ b_ih,
                                            float* __restrict__ gix) {
    int b = blockIdx.x;
    int n = blockIdx.y * 256 + threadIdx.x;      // < 1536
    __shared__ __align__(16) float xs[INP];
    for (int i = threadIdx.x; i < INP; i += 256) xs[i] = x[(size_t)b * INP + i];
    __syncthreads();
    const float4* w  = (const float4*)(w_ih + (size_t)n * 1536);
    const float4* xv = (const float4*)xs;
    float acc = 0.f;
    for (int kc = 0; kc < 256; ++kc) acc += dot4(w[kc], xv[kc]);
    gix[(size_t)b * 1536 + n] = acc + b_ih[n];
}

// mmu GEMM: (16 NPUs per block) x 1537 used output rows
__global__ __launch_bounds__(256) void kMmu(const float* __restrict__ hidden,
                                            const float* __restrict__ mmu_w,
                                            const float* __restrict__ mmu_b,
                                            float* __restrict__ query, float* __restrict__ wkey,
                                            float* __restrict__ wval,  float* __restrict__ wgate,
                                            const int* __restrict__ anp) {
    int b = blockIdx.x, at = blockIdx.y, t = threadIdx.x;
    int A = *anp;
    int a0 = at * 16;
    __shared__ __align__(16) float regs[16 * RR];
    const float4* src = (const float4*)(hidden + ((size_t)b * NPU + a0) * RR);
#pragma unroll
    for (int j = 0; j < 8; ++j) ((float4*)regs)[t + j * 256] = src[t + j * 256];
    __syncthreads();
    for (int n = t; n < MMU_USED; n += 256) {
        const float4* w = (const float4*)(mmu_w + (size_t)n * RR);
        float acc[16];
#pragma unroll
        for (int a = 0; a < 16; ++a) acc[a] = 0.f;
        for (int kc = 0; kc < 128; ++kc) {
            float4 wv = w[kc];
#pragma unroll
            for (int a = 0; a < 16; ++a)
                acc[a] += dot4(wv, ((const float4*)regs)[a * 128 + kc]);  // LDS broadcast
        }
        float bias = mmu_b[n];
#pragma unroll
        for (int a = 0; a < 16; ++a) {
            int aa = a0 + a;
            if (aa >= A) continue;
            float v = acc[a] + bias;
            size_t base = (size_t)b * NPU + aa;
            if (n < 512)       query[base * DD + n] = v;
            else if (n < 1024) wkey [base * DD + n - 512] = v;
            else if (n < 1536) wval [base * DD + n - 1024] = v;
            else               wgate[base] = 1.f / (1.f + __expf(-v));
        }
    }
}

// flash read-attention + write-score stats. 16 a's/block, 16 threads/a, 32 d/thread.
__global__ __launch_bounds__(256) void kAttnRead(const float* __restrict__ mem,
                                                 const float* __restrict__ query,
                                                 const float* __restrict__ wkey,
                                                 float* __restrict__ rdata,
                                                 __hip_bfloat16* __restrict__ swsc,
                                                 float* __restrict__ wmax, float* __restrict__ wsum,
                                                 const int* __restrict__ anp) {
    int b = blockIdx.x, at = blockIdx.y, t = threadIdx.x;
    int A = *anp;
    int a_loc = t >> 4, g = t & 15;
    int a = at * 16 + a_loc;
    bool act = a < A;
    int d0 = g * 32;
    __shared__ __align__(16) float smem[8 * DD];
    float qs[32], ks[32], acc[32];
    {
        const float4* qp = (const float4*)(query + ((size_t)b * NPU + a) * DD + d0);
        const float4* kp = (const float4*)(wkey  + ((size_t)b * NPU + a) * DD + d0);
#pragma unroll
        for (int i = 0; i < 8; ++i) {
            float4 qv = act ? qp[i] : make_float4(0.f, 0.f, 0.f, 0.f);
            float4 kv = act ? kp[i] : make_float4(0.f, 0.f, 0.f, 0.f);
            qs[4*i] = qv.x; qs[4*i+1] = qv.y; qs[4*i+2] = qv.z; qs[4*i+3] = qv.w;
            ks[4*i] = kv.x; ks[4*i+1] = kv.y; ks[4*i+2] = kv.z; ks[4*i+3] = kv.w;
        }
    }
#pragma unroll
    for (int i = 0; i < 32; ++i) acc[i] = 0.f;
    float m_r = -INFINITY, l_r = 0.f, m_w = -INFINITY, l_w = 0.f;
    const float inv = 0.044194173824159216f;  // 1/sqrt(512)
    const float4* mb = (const float4*)(mem + (size_t)b * MEMN * DD);
    for (int m0 = 0; m0 < MEMN; m0 += 8) {
        __syncthreads();
        const float4* s4 = mb + (size_t)m0 * (DD / 4);
#pragma unroll
        for (int j = 0; j < 4; ++j) ((float4*)smem)[t + j * 256] = s4[t + j * 256];
        __syncthreads();
#pragma unroll 1
        for (int mi = 0; mi < 8; ++mi) {
            float mv[32];
            const float4* row = (const float4*)(smem + mi * DD + d0);
            float sq = 0.f, sw = 0.f;
#pragma unroll
            for (int i = 0; i < 8; ++i) {
                float4 v = row[i];
                mv[4*i] = v.x; mv[4*i+1] = v.y; mv[4*i+2] = v.z; mv[4*i+3] = v.w;
            }
#pragma unroll
            for (int i = 0; i < 32; ++i) { sq += qs[i] * mv[i]; sw += ks[i] * mv[i]; }
#pragma unroll
            for (int off = 8; off >= 1; off >>= 1) {   // reduce within 16-lane group
                sq += __shfl_xor(sq, off);
                sw += __shfl_xor(sw, off);
            }
            sq *= inv; sw *= inv;
            if (act && g == 0)
                swsc[((size_t)b * NPU + a) * MEMN + m0 + mi] = __float2bfloat16(sw);
            float nm = fmaxf(m_r, sq);
            float scale = __expf(m_r - nm);
            float pv = __expf(sq - nm);
            l_r = l_r * scale + pv; m_r = nm;
#pragma unroll
            for (int i = 0; i < 32; ++i) acc[i] = acc[i] * scale + pv * mv[i];
            float nw = fmaxf(m_w, sw);
            l_w = l_w * __expf(m_w - nw) + __expf(sw - nw);
            m_w = nw;
        }
    }
    if (act) {
        float invl = 1.f / l_r;
        float4* rp = (float4*)(rdata + ((size_t)b * NPU + a) * DD + d0);
#pragma unroll
        for (int i = 0; i < 8; ++i)
            rp[i] = make_float4(acc[4*i] * invl, acc[4*i+1] * invl, acc[4*i+2] * invl, acc[4*i+3] * invl);
        if (g == 0) { wmax[(size_t)b * NPU + a] = m_w; wsum[(size_t)b * NPU + a] = l_w; }
    }
}

// GRU cell, 16 a's per block, thread owns j and j+256
__global__ __launch_bounds__(256) void kGru(const float* __restrict__ hidden,
                                            const float* __restrict__ rdata,
                                            const float* __restrict__ w_ih,
                                            const float* __restrict__ w_hh,
                                            const float* __restrict__ b_hh,
                                            const float* __restrict__ gix,
                                            float* __restrict__ out_hidden,
                                            const int* __restrict__ anp) {
    int b = blockIdx.x, at = blockIdx.y, t = threadIdx.x;
    int A = *anp;
    int a0 = at * 16;
    __shared__ __align__(16) float rd[16 * RR];
    __shared__ __align__(16) float hh[16 * RR];
    const float4* s1 = (const float4*)(rdata  + ((size_t)b * NPU + a0) * DD);
    const float4* s2 = (const float4*)(hidden + ((size_t)b * NPU + a0) * RR);
#pragma unroll
    for (int j = 0; j < 8; ++j) {
        ((float4*)rd)[t + j * 256] = s1[t + j * 256];
        ((float4*)hh)[t + j * 256] = s2[t + j * 256];
    }
    __syncthreads();
#pragma unroll 1
    for (int jj = 0; jj < 2; ++jj) {
        int j = t + jj * 256;
        float rv[16], zv[16];
#pragma unroll 1
        for (int gate = 0; gate < 3; ++gate) {
            int n = gate * RR + j;
            const float4* wi = (const float4*)(w_ih + (size_t)n * 1536 + 1024);
            const float4* wh = (const float4*)(w_hh + (size_t)n * RR);
            float ai[16], ah[16];
#pragma unroll
            for (int a = 0; a < 16; ++a) { ai[a] = 0.f; ah[a] = 0.f; }
            for (int kc = 0; kc < 128; ++kc) {
                float4 wiv = wi[kc];
                float4 whv = wh[kc];
#pragma unroll
                for (int a = 0; a < 16; ++a) {
                    ai[a] += dot4(wiv, ((const float4*)rd)[a * 128 + kc]);
                    ah[a] += dot4(whv, ((const float4*)hh)[a * 128 + kc]);
                }
            }
            float gx = gix[(size_t)b * 1536 + n];
            float bh = b_hh[n];
            if (gate == 0) {
#pragma unroll
                for (int a = 0; a < 16; ++a) rv[a] = 1.f / (1.f + __expf(-(ai[a] + gx + ah[a] + bh)));
            } else if (gate == 1) {
#pragma unroll
                for (int a = 0; a < 16; ++a) zv[a] = 1.f / (1.f + __expf(-(ai[a] + gx + ah[a] + bh)));
            } else {
#pragma unroll
                for (int a = 0; a < 16; ++a) {
                    int aa = a0 + a;
                    if (aa >= A) continue;
                    float nn = tanhf(ai[a] + gx + rv[a] * (ah[a] + bh));
                    float h = hh[a * RR + j];
                    out_hidden[((size_t)b * NPU + aa) * RR + j] = (1.f - zv[a]) * nn + zv[a] * h;
                }
            }
        }
    }
}

// write attention combine + memory update. 16 m rows per block.
#define MT 16
__global__ __launch_bounds__(256) void kWrite(const float* __restrict__ mem,
                                              const float* __restrict__ wval,
                                              const float* __restrict__ wgate,
                                              const float* __restrict__ wmax,
                                              const float* __restrict__ wsum,
                                              const __hip_bfloat16* __restrict__ swsc,
                                              float* __restrict__ out_mem,
                                              const int* __restrict__ anp) {
    int b = blockIdx.x, mtile = blockIdx.y, t = threadIdx.x;
    int A = *anp;
    int m0 = mtile * MT;
    __shared__ __align__(16) float cL[NPU * MT];
    __shared__ float ec[NPU], wm[NPU];
    __shared__ float twL[MT];
    __shared__ __align__(16) float cv[MT * 516];   // pitch 516 floats (2064B, 16B aligned)
    {
        int a = t;
        float e = 0.f, w = 0.f;
        if (a < A) {
            e = wgate[(size_t)b * NPU + a] / wsum[(size_t)b * NPU + a];
            w = wmax[(size_t)b * NPU + a];
        }
        ec[a] = e; wm[a] = w;
    }
    __syncthreads();
#pragma unroll
    for (int i = 0; i < MT; ++i) {
        int flat = t + i * 256;          // flat = a*MT + mi
        int a = flat >> 4, mi = flat & 15;
        float s = __bfloat162float(swsc[((size_t)b * NPU + a) * MEMN + m0 + mi]);
        cL[flat] = ec[a] * __expf(s - wm[a]);
    }
    __syncthreads();
    int mi = t & 15, dg = t >> 4;        // d slice = dg*32 .. +31
    float acc[32];
#pragma unroll
    for (int i = 0; i < 32; ++i) acc[i] = 0.f;
    float tws = 0.f;
    for (int a = 0; a < NPU; ++a) {
        float ca = cL[a * MT + mi];
        tws += ca;
        const float4* wr = (const float4*)(wval + ((size_t)b * NPU + a) * DD + dg * 32);
#pragma unroll
        for (int i = 0; i < 8; ++i) {
            float4 v = wr[i];
            acc[4*i]   += ca * v.x; acc[4*i+1] += ca * v.y;
            acc[4*i+2] += ca * v.z; acc[4*i+3] += ca * v.w;
        }
    }
    if (t < MT) twL[t] = fminf(fmaxf(tws, 0.f), 1.f);
#pragma unroll
    for (int i = 0; i < 8; ++i)
        *(float4*)&cv[mi * 516 + dg * 32 + 4 * i] =
            make_float4(acc[4*i], acc[4*i+1], acc[4*i+2], acc[4*i+3]);
    __syncthreads();
    const float4* min4 = (const float4*)(mem     + ((size_t)b * MEMN + m0) * DD);
    float4*      mout4 = (float4*)      (out_mem + ((size_t)b * MEMN + m0) * DD);
#pragma unroll
    for (int i = 0; i < 8; ++i) {
        int f4 = t + i * 256;
        int row = f4 >> 7, col = (f4 & 127) * 4;
        float tw = twL[row];
        float4 mv = min4[f4];
        float4 cvv = *(const float4*)&cv[row * 516 + col];
        mout4[f4] = make_float4(mv.x * (1.f - tw) + cvv.x, mv.y * (1.f - tw) + cvv.y,
                                mv.z * (1.f - tw) + cvv.z, mv.w * (1.f - tw) + cvv.w);
    }
}

__device__ __forceinline__ float blockSum(float v, float* red, int t) {
#pragma unroll
    for (int off = 32; off >= 1; off >>= 1) v += __shfl_xor(v, off);
    __syncthreads();
    if ((t & 63) == 0) red[t >> 6] = v;
    __syncthreads();
    return red[0] + red[1] + red[2] + red[3];
}
__device__ __forceinline__ float blockMax(float v, float* red, int t) {
#pragma unroll
    for (int off = 32; off >= 1; off >>= 1) v = fmaxf(v, __shfl_xor(v, off));
    __syncthreads();
    if ((t & 63) == 0) red[t >> 6] = v;
    __syncthreads();
    return fmaxf(fmaxf(red[0], red[1]), fmaxf(red[2], red[3]));
}

// collapsed output head: softmax over a of r.new_regs, then proj(out(u)), then LN
__global__ __launch_bounds__(256) void kOut(const float* __restrict__ nr,
                                            const float* __restrict__ rvec,
                                            const float* __restrict__ out_w,
                                            const float* __restrict__ out_b,
                                            const float* __restrict__ proj_w,
                                            const float* __restrict__ proj_b,
                                            const float* __restrict__ ln_g,
                                            const float* __restrict__ ln_b,
                                            float* __restrict__ out,
                                            const int* __restrict__ anp) {
    int b = blockIdx.x, t = threadIdx.x;
    int A = *anp;
    __shared__ float sa[NPU];
    __shared__ __align__(16) float uL[RR];
    __shared__ __align__(16) float npuL[INP];
    __shared__ float red[4];
    __shared__ float aggS[HIDN];
    const float inv_h = 0.022097086912079608f;  // 1/sqrt(2048)
    float s = -INFINITY;
    if (t < A) {
        const float4* row = (const float4*)(nr + ((size_t)b * NPU + t) * RR);
        const float4* rv4 = (const float4*)rvec;
        float acc = 0.f;
        for (int i = 0; i < 128; ++i) acc += dot4(row[i], rv4[i]);
        s = acc * inv_h;
    }
    float mx = blockMax(s, red, t);
    float e = (t < A) ? __expf(s - mx) : 0.f;
    float tot = blockSum(e, red, t);
    sa[t] = e / tot;
    __syncthreads();
    float u0 = 0.f, u1 = 0.f;
    for (int a = 0; a < A; ++a) {
        float w = sa[a];
        const float* row = nr + ((size_t)b * NPU + a) * RR;
        u0 += w * row[t];
        u1 += w * row[t + 256];
    }
    uL[t] = u0; uL[t + 256] = u1;
    __syncthreads();
#pragma unroll 1
    for (int k = 0; k < 4; ++k) {
        int i = t + k * 256;
        const float4* w4 = (const float4*)(out_w + (size_t)i * RR);
        float acc = 0.f;
        for (int kc = 0; kc < 128; ++kc) acc += dot4(w4[kc], ((const float4*)uL)[kc]);
        npuL[i] = acc + out_b[i];
    }
    __syncthreads();
    float ag[8];
#pragma unroll 1
    for (int k = 0; k < 8; ++k) {
        int h = t + k * 256;
        const float4* w4 = (const float4*)(proj_w + (size_t)h * INP);
        float acc = 0.f;
        for (int kc = 0; kc < 256; ++kc) acc += dot4(w4[kc], ((const float4*)npuL)[kc]);
        ag[k] = acc + proj_b[h];
        aggS[h] = ag[k];
    }
    (void)aggS;
    float ms = 0.f;
#pragma unroll
    for (int k = 0; k < 8; ++k) ms += ag[k];
    float mu = blockSum(ms, red, t) * (1.f / HIDN);
    float vs = 0.f;
#pragma unroll
    for (int k = 0; k < 8; ++k) { float d = ag[k] - mu; vs += d * d; }
    float var = blockSum(vs, red, t) * (1.f / HIDN);
    float rs = rsqrtf(var + 1e-5f);
#pragma unroll
    for (int k = 0; k < 8; ++k) {
        int h = t + k * 256;
        out[(size_t)b * HIDN + h] = (ag[k] - mu) * rs * ln_g[h] + ln_b[h];
    }
}

extern "C" void kernel_launch(void* const* d_in, const int* in_sizes, int n_in,
                              void* d_out, int out_size, void* d_ws, size_t ws_size,
                              hipStream_t stream) {
    (void)in_sizes; (void)n_in; (void)out_size; (void)ws_size;
    const float* x      = (const float*)d_in[0];
    const float* hidden = (const float*)d_in[1];
    const float* mem    = (const float*)d_in[2];
    const float* mmu_w  = (const float*)d_in[3];
    const float* mmu_b  = (const float*)d_in[4];
    const float* w_ih   = (const float*)d_in[5];
    const float* b_ih   = (const float*)d_in[6];
    const float* w_hh   = (const float*)d_in[7];
    const float* b_hh   = (const float*)d_in[8];
    const float* out_w  = (const float*)d_in[9];
    const float* out_b  = (const float*)d_in[10];
    const float* agg_q  = (const float*)d_in[11];
    const float* proj_w = (const float*)d_in[12];
    const float* proj_b = (const float*)d_in[13];
    const float* ln_g   = (const float*)d_in[14];
    const float* ln_b   = (const float*)d_in[15];
    const int*   anp    = (const int*)d_in[16];

    float* ws = (float*)d_ws;
    float* query = ws + OFF_QUERY;
    float* wkey  = ws + OFF_WKEY;
    float* wval  = ws + OFF_WVAL;
    float* rdata = ws + OFF_RDATA;
    float* wgate = ws + OFF_WGATE;
    float* wmaxp = ws + OFF_WMAX;
    float* wsump = ws + OFF_WSUM;
    float* gix   = ws + OFF_GIX;
    float* pvec  = ws + OFF_P;
    float* rvec  = ws + OFF_R;
    __hip_bfloat16* swsc = (__hip_bfloat16*)((char*)d_ws + OFF_FEND * 4);

    float* outv = (float*)d_out;
    float* outh = outv + (size_t)BB * HIDN;
    float* outm = outh + (size_t)BB * NPU * RR;

    kP0<<<4, 256, 0, stream>>>(proj_w, agg_q, pvec);
    kP1<<<2, 256, 0, stream>>>(out_w, pvec, rvec);
    kCopyHidden<<<2048, 256, 0, stream>>>((const float4*)hidden, (float4*)outh);
    kGix<<<dim3(BB, 6), 256, 0, stream>>>(x, w_ih, b_ih, gix);
    kMmu<<<dim3(BB, 16), 256, 0, stream>>>(hidden, mmu_w, mmu_b, query, wkey, wval, wgate, anp);
    kAttnRead<<<dim3(BB, 16), 256, 0, stream>>>(mem, query, wkey, rdata, swsc, wmaxp, wsump, anp);
    kGru<<<dim3(BB, 16), 256, 0, stream>>>(hidden, rdata, w_ih, w_hh, b_hh, gix, outh, anp);
    kWrite<<<dim3(BB, MEMN / MT), 256, 0, stream>>>(mem, wval, wgate, wmaxp, wsump, swsc, outm, anp);
    kOut<<<BB, 256, 0, stream>>>(outh, rvec, out_w, out_b, proj_w, proj_b, ln_g, ln_b, outv, anp);
}